// Round 5
// baseline (593.586 us; speedup 1.0000x reference)
//
#include <hip/hip_runtime.h>
#include <cmath>

typedef __bf16  v8bf  __attribute__((ext_vector_type(8)));
typedef float   v4f   __attribute__((ext_vector_type(4)));

#define HH 56
#define WW2 56
#define SS 3
#define HEADS 6
#define DIM 192
#define HID 768
#define NTOK 49
#define NWIN 2048            // BATCH * 64
#define MTOT (NWIN * NTOK)   // 100352
#define SCALE 0.17677669529663687f

// async global->LDS, 16B per lane. LDS dest must be wave-uniform base + lane*16.
__device__ __forceinline__ void async_cp16(const __bf16* g, __bf16* l) {
    __builtin_amdgcn_global_load_lds(
        (const __attribute__((address_space(1))) void*)g,
        (__attribute__((address_space(3))) void*)l,
        16, 0, 0);
}

// ---------------------------------------------------------------------------
// Weight transpose + f32->bf16 cast: out[n*K + k] = (bf16)in[k*N + n]
// ---------------------------------------------------------------------------
__global__ void k_transpose(const float* __restrict__ in, __bf16* __restrict__ out,
                            int K, int N) {
    int idx = blockIdx.x * 256 + threadIdx.x;
    if (idx >= K * N) return;
    int n = idx / K, k = idx - n * K;
    out[idx] = (__bf16)in[k * N + n];
}

// ---------------------------------------------------------------------------
// Precompute bias tables: bias_tab[type][h][m][n], type in {0=interior,
// 1=right-edge, 2=bottom-edge, 3=corner}. Includes rel-pos bias, shift mask,
// and -1e9 padding for cols m>=49.  n-contiguous so attention loads float4.
// ---------------------------------------------------------------------------
__global__ void k_bias(const float* __restrict__ rpb, float* __restrict__ bt) {
    int type = blockIdx.x, h = blockIdx.y;
    for (int idx = threadIdx.x; idx < 4096; idx += 256) {
        int m = idx >> 6, n = idx & 63;
        float v;
        if (m >= 49) v = -1e9f;
        else if (n >= 49) v = 0.f;
        else {
            int ni = n / 7, nj = n % 7, mi = m / 7, mj = m % 7;
            v = rpb[((ni - mi + 6) * 13 + (nj - mj + 6)) * 6 + h];
            int rin = (type & 2) ? ((ni < 4) ? 1 : 2) : 0;
            int rjn = (type & 1) ? ((nj < 4) ? 1 : 2) : 0;
            int rim = (type & 2) ? ((mi < 4) ? 1 : 2) : 0;
            int rjm = (type & 1) ? ((mj < 4) ? 1 : 2) : 0;
            if (rin * 3 + rjn != rim * 3 + rjm) v -= 100.f;
        }
        bt[((size_t)(type * HEADS + h) * 64 + m) * 64 + n] = v;
    }
}

// ---------------------------------------------------------------------------
// LN1 + cyclic shift(-3,-3) + window partition. x f32 -> xw bf16 [w*49+p][c].
// ---------------------------------------------------------------------------
__global__ __launch_bounds__(256) void k_ln1win(const float* __restrict__ x,
                                                const float* __restrict__ g,
                                                const float* __restrict__ bt,
                                                __bf16* __restrict__ xw) {
    int wv = threadIdx.x >> 6, lane = threadIdx.x & 63;
    int t = blockIdx.x * 4 + wv;
    int w = t / NTOK, p = t - w * NTOK;
    int b = w >> 6, wi = w & 63;
    int i = (wi >> 3) * 7 + p / 7;
    int j = (wi & 7) * 7 + p % 7;
    int io = i + SS; if (io >= HH) io -= HH;
    int jo = j + SS; if (jo >= WW2) jo -= WW2;
    const float* src = x + ((size_t)(b * 3136 + io * 56 + jo)) * DIM;
    float v0 = src[lane], v1 = src[lane + 64], v2 = src[lane + 128];
    float s = v0 + v1 + v2, s2 = v0 * v0 + v1 * v1 + v2 * v2;
    #pragma unroll
    for (int off = 1; off < 64; off <<= 1) {
        s  += __shfl_xor(s, off);
        s2 += __shfl_xor(s2, off);
    }
    float mu = s * (1.f / 192.f);
    float rstd = rsqrtf(s2 * (1.f / 192.f) - mu * mu + 1e-5f);
    __bf16* dst = xw + (size_t)t * DIM;
    dst[lane]       = (__bf16)((v0 - mu) * rstd * g[lane]       + bt[lane]);
    dst[lane + 64]  = (__bf16)((v1 - mu) * rstd * g[lane + 64]  + bt[lane + 64]);
    dst[lane + 128] = (__bf16)((v2 - mu) * rstd * g[lane + 128] + bt[lane + 128]);
}

// ---------------------------------------------------------------------------
// 128x128-tile MFMA GEMM: C = A[MxK] * Wt[NxK]^T + bias.
// MODE 0: qkv scatter -> qb/kb/vb [w,h,t,32] bf16 (q scaled); kb/vb derived.
// MODE 1: proj -> outf = x1 (window-reverse scatter) + xres, f32  (fallback)
// MODE 2: fc1  -> outb [M][768] bf16 with exact-erf GELU
// ---------------------------------------------------------------------------
template<int KDIM, int NDIM, int MODE>
__global__ __launch_bounds__(256) void k_gemm128(const __bf16* __restrict__ A,
                                                 const __bf16* __restrict__ Wt,
                                                 const float* __restrict__ bias,
                                                 __bf16* __restrict__ outb,
                                                 const float* __restrict__ x1in,
                                                 float* __restrict__ outf,
                                                 const float* __restrict__ xres) {
    __shared__ __bf16 lA[128 * 32];
    __shared__ __bf16 lB[128 * 32];
    const int tid = threadIdx.x;
    const int m0 = blockIdx.x * 128, n0 = blockIdx.y * 128;
    const int wv = tid >> 6, lane = tid & 63;
    const int wm = (wv >> 1) * 64, wn = (wv & 1) * 64;
    const int lrow = lane & 15, lq = lane >> 4;
    const int grow = tid >> 2, gkc = (tid & 3) * 8;
    v4f acc[4][4] = {};
    for (int kk = 0; kk < KDIM; kk += 32) {
        #pragma unroll
        for (int c = 0; c < 2; c++) {
            int r = grow + c * 64;
            async_cp16(A + (size_t)(m0 + r) * KDIM + kk + gkc, lA + tid * 8 + c * 2048);
            int rb = n0 + r;
            if (NDIM % 128) rb = (rb < NDIM) ? rb : (NDIM - 1);
            async_cp16(Wt + (size_t)rb * KDIM + kk + gkc, lB + tid * 8 + c * 2048);
        }
        __syncthreads();
        v8bf af[4], bf[4];
        #pragma unroll
        for (int i = 0; i < 4; i++) {
            af[i] = *(const v8bf*)(lA + (wm + i * 16 + lrow) * 32 + lq * 8);
            bf[i] = *(const v8bf*)(lB + (wn + i * 16 + lrow) * 32 + lq * 8);
        }
        #pragma unroll
        for (int i = 0; i < 4; i++)
        #pragma unroll
        for (int j = 0; j < 4; j++)
            acc[i][j] = __builtin_amdgcn_mfma_f32_16x16x32_bf16(af[i], bf[j], acc[i][j], 0, 0, 0);
        __syncthreads();
    }
    #pragma unroll
    for (int i = 0; i < 4; i++)
    #pragma unroll
    for (int j = 0; j < 4; j++) {
        int col = n0 + wn + j * 16 + lrow;
        if (NDIM % 128 && col >= NDIM) continue;
        float bv = bias[col];
        #pragma unroll
        for (int r = 0; r < 4; r++) {
            int row = m0 + wm + i * 16 + lq * 4 + r;
            float v = acc[i][j][r] + bv;
            if (MODE == 0) {
                __bf16* kbp = outb + (size_t)MTOT * DIM;
                __bf16* vbp = kbp + (size_t)MTOT * DIM;
                int which = col / DIM, rem = col - which * DIM;
                int hh = rem >> 5, d = rem & 31;
                int w = row / NTOK, p = row - w * NTOK;
                size_t off = ((size_t)(w * HEADS + hh) * NTOK + p) * 32 + d;
                if (which == 0)      outb[off] = (__bf16)(v * SCALE);
                else if (which == 1) kbp[off] = (__bf16)v;
                else                 vbp[off] = (__bf16)v;
            } else if (MODE == 2) {
                float ge = 0.5f * v * (1.f + erff(v * 0.70710678118654752f));
                outb[(size_t)row * HID + col] = (__bf16)ge;
            } else {  // proj fallback: window-reverse + unshift + residual
                int w = row / NTOK, p = row - w * NTOK;
                int bimg = w >> 6, wi = w & 63;
                int ii = (wi >> 3) * 7 + p / 7;
                int jj = (wi & 7) * 7 + p % 7;
                int io = ii + SS; if (io >= HH) io -= HH;
                int jo = jj + SS; if (jo >= WW2) jo -= WW2;
                size_t o = ((size_t)(bimg * 3136 + io * 56 + jo)) * DIM + col;
                outf[o] = v + xres[o];
            }
        }
    }
}

// ---------------------------------------------------------------------------
// proj GEMM 128x192 tile + fused window-reverse + residual -> x1 f32 AND
// LN2 -> a2 bf16.  4 waves as 2 row-halves x 2 col-halves (64x96 each).
// Row stats: shfl over 16 col-lanes, halves combined via small LDS.
// ---------------------------------------------------------------------------
__global__ __launch_bounds__(256) void k_projln(const __bf16* __restrict__ A,
                                                const __bf16* __restrict__ Wt,
                                                const float* __restrict__ bias,
                                                const float* __restrict__ xres,
                                                const float* __restrict__ n2g,
                                                const float* __restrict__ n2b,
                                                float* __restrict__ x1,
                                                __bf16* __restrict__ a2) {
    __shared__ __bf16 lA[128 * 32];
    __shared__ __bf16 lB[192 * 32];
    __shared__ float rsum[128][2];
    __shared__ float rsq[128][2];
    const int tid = threadIdx.x;
    const int m0 = blockIdx.x * 128;
    const int wv = tid >> 6, lane = tid & 63;
    const int wm = (wv >> 1) * 64, wn = (wv & 1) * 96;
    const int half = wv & 1;
    const int lrow = lane & 15, lq = lane >> 4;
    const int grow = tid >> 2, gkc = (tid & 3) * 8;
    v4f acc[4][6] = {};
    for (int kk = 0; kk < 192; kk += 32) {
        #pragma unroll
        for (int c = 0; c < 2; c++)
            async_cp16(A + (size_t)(m0 + grow + c * 64) * 192 + kk + gkc, lA + tid * 8 + c * 2048);
        #pragma unroll
        for (int c = 0; c < 3; c++)
            async_cp16(Wt + (size_t)(grow + c * 64) * 192 + kk + gkc, lB + tid * 8 + c * 2048);
        __syncthreads();
        v8bf af[4], bf[6];
        #pragma unroll
        for (int i = 0; i < 4; i++)
            af[i] = *(const v8bf*)(lA + (wm + i * 16 + lrow) * 32 + lq * 8);
        #pragma unroll
        for (int j = 0; j < 6; j++)
            bf[j] = *(const v8bf*)(lB + (wn + j * 16 + lrow) * 32 + lq * 8);
        #pragma unroll
        for (int i = 0; i < 4; i++)
        #pragma unroll
        for (int j = 0; j < 6; j++)
            acc[i][j] = __builtin_amdgcn_mfma_f32_16x16x32_bf16(af[i], bf[j], acc[i][j], 0, 0, 0);
        __syncthreads();
    }
    int orows[4][4];
    #pragma unroll
    for (int i = 0; i < 4; i++)
    #pragma unroll
    for (int r = 0; r < 4; r++) {
        int row_l = wm + i * 16 + lq * 4 + r;
        int row = m0 + row_l;
        int w = row / NTOK, p = row - w * NTOK;
        int bimg = w >> 6, wi = w & 63;
        int ii = (wi >> 3) * 7 + p / 7;
        int jj = (wi & 7) * 7 + p % 7;
        int io = ii + SS; if (io >= HH) io -= HH;
        int jo = jj + SS; if (jo >= WW2) jo -= WW2;
        orows[i][r] = (bimg * 3136 + io * 56 + jo) * DIM;
        float s = 0.f, s2 = 0.f;
        #pragma unroll
        for (int j = 0; j < 6; j++) {
            int col = wn + j * 16 + lrow;
            float v = acc[i][j][r] + bias[col] + xres[(size_t)orows[i][r] + col];
            x1[(size_t)orows[i][r] + col] = v;
            acc[i][j][r] = v;
            s += v; s2 += v * v;
        }
        #pragma unroll
        for (int off = 1; off < 16; off <<= 1) {
            s  += __shfl_xor(s, off);
            s2 += __shfl_xor(s2, off);
        }
        if (lrow == 0) { rsum[row_l][half] = s; rsq[row_l][half] = s2; }
    }
    __syncthreads();
    #pragma unroll
    for (int i = 0; i < 4; i++)
    #pragma unroll
    for (int r = 0; r < 4; r++) {
        int row_l = wm + i * 16 + lq * 4 + r;
        float mu = (rsum[row_l][0] + rsum[row_l][1]) * (1.f / 192.f);
        float var = (rsq[row_l][0] + rsq[row_l][1]) * (1.f / 192.f) - mu * mu;
        float rstd = rsqrtf(var + 1e-5f);
        #pragma unroll
        for (int j = 0; j < 6; j++) {
            int col = wn + j * 16 + lrow;
            float v = acc[i][j][r];
            a2[(size_t)orows[i][r] + col] = (__bf16)((v - mu) * rstd * n2g[col] + n2b[col]);
        }
    }
}

// ---------------------------------------------------------------------------
// fc2 GEMM 128x192 tile, K=768: out = hid @ fc2 + bias + x1.  hid read once.
// ---------------------------------------------------------------------------
__global__ __launch_bounds__(256) void k_fc2(const __bf16* __restrict__ A,
                                             const __bf16* __restrict__ Wt,
                                             const float* __restrict__ bias,
                                             const float* __restrict__ x1,
                                             float* __restrict__ out) {
    __shared__ __bf16 lA[128 * 32];
    __shared__ __bf16 lB[192 * 32];
    const int tid = threadIdx.x;
    const int m0 = blockIdx.x * 128;
    const int wv = tid >> 6, lane = tid & 63;
    const int wm = (wv >> 1) * 64, wn = (wv & 1) * 96;
    const int lrow = lane & 15, lq = lane >> 4;
    const int grow = tid >> 2, gkc = (tid & 3) * 8;
    v4f acc[4][6] = {};
    for (int kk = 0; kk < HID; kk += 32) {
        #pragma unroll
        for (int c = 0; c < 2; c++)
            async_cp16(A + (size_t)(m0 + grow + c * 64) * HID + kk + gkc, lA + tid * 8 + c * 2048);
        #pragma unroll
        for (int c = 0; c < 3; c++)
            async_cp16(Wt + (size_t)(grow + c * 64) * HID + kk + gkc, lB + tid * 8 + c * 2048);
        __syncthreads();
        v8bf af[4], bf[6];
        #pragma unroll
        for (int i = 0; i < 4; i++)
            af[i] = *(const v8bf*)(lA + (wm + i * 16 + lrow) * 32 + lq * 8);
        #pragma unroll
        for (int j = 0; j < 6; j++)
            bf[j] = *(const v8bf*)(lB + (wn + j * 16 + lrow) * 32 + lq * 8);
        #pragma unroll
        for (int i = 0; i < 4; i++)
        #pragma unroll
        for (int j = 0; j < 6; j++)
            acc[i][j] = __builtin_amdgcn_mfma_f32_16x16x32_bf16(af[i], bf[j], acc[i][j], 0, 0, 0);
        __syncthreads();
    }
    #pragma unroll
    for (int i = 0; i < 4; i++)
    #pragma unroll
    for (int j = 0; j < 6; j++) {
        int col = wn + j * 16 + lrow;
        float bv = bias[col];
        #pragma unroll
        for (int r = 0; r < 4; r++) {
            int row = m0 + wm + i * 16 + lq * 4 + r;
            size_t o = (size_t)row * DIM + col;
            out[o] = acc[i][j][r] + bv + x1[o];
        }
    }
}

// ---------------------------------------------------------------------------
// MFMA windowed attention: one wave per (window, head), 64-thread blocks.
// ---------------------------------------------------------------------------
__global__ __launch_bounds__(64) void k_attn_mfma(const __bf16* __restrict__ qb,
                                                  const float* __restrict__ bias_tab,
                                                  __bf16* __restrict__ ao) {
    __shared__ __bf16 Pl[64 * 72];
    __shared__ __bf16 VTl[32 * 72];
    const __bf16* kb = qb + (size_t)MTOT * DIM;
    const __bf16* vb = kb + (size_t)MTOT * DIM;
    int wh = blockIdx.x;
    int w = wh / HEADS, h = wh - w * HEADS;
    int lane = threadIdx.x & 63;
    int c = lane & 15, q = lane >> 4;
    const size_t base = (size_t)wh * (NTOK * 32);

    for (int idx = lane; idx < 32 * 16; idx += 64)
        VTl[(idx >> 4) * 72 + 48 + (idx & 15)] = (__bf16)0.f;
    #pragma unroll
    for (int it = 0; it < 4; it++) {
        int idx = it * 64 + lane;
        if (idx < NTOK * 4) {
            int t = idx >> 2, d0 = (idx & 3) * 8;
            v8bf vv = *(const v8bf*)(vb + base + t * 32 + d0);
            #pragma unroll
            for (int ii = 0; ii < 8; ii++) VTl[(d0 + ii) * 72 + t] = vv[ii];
        }
    }
    v8bf af[4], bf[4];
    #pragma unroll
    for (int rt = 0; rt < 4; rt++) {
        int t = rt * 16 + c; t = (t > 48) ? 48 : t;
        af[rt] = *(const v8bf*)(qb + base + t * 32 + q * 8);
        bf[rt] = *(const v8bf*)(kb + base + t * 32 + q * 8);
    }
    v4f S[4][4] = {};
    #pragma unroll
    for (int rt = 0; rt < 4; rt++)
    #pragma unroll
    for (int ct = 0; ct < 4; ct++)
        S[rt][ct] = __builtin_amdgcn_mfma_f32_16x16x32_bf16(af[rt], bf[ct], S[rt][ct], 0, 0, 0);
    int wi = w & 63;
    int type = (((wi >> 3) == 7) ? 2 : 0) + (((wi & 7) == 7) ? 1 : 0);
    const float* bt = bias_tab + (size_t)(type * HEADS + h) * 4096;
    #pragma unroll
    for (int rt = 0; rt < 4; rt++)
    #pragma unroll
    for (int ct = 0; ct < 4; ct++) {
        v4f bv = *(const v4f*)(bt + (ct * 16 + c) * 64 + rt * 16 + q * 4);
        S[rt][ct] += bv;
    }
    v4f mx4[4], inv4[4];
    #pragma unroll
    for (int rt = 0; rt < 4; rt++) {
        v4f m;
        #pragma unroll
        for (int r = 0; r < 4; r++)
            m[r] = fmaxf(fmaxf(S[rt][0][r], S[rt][1][r]), fmaxf(S[rt][2][r], S[rt][3][r]));
        #pragma unroll
        for (int off = 1; off < 16; off <<= 1) {
            #pragma unroll
            for (int r = 0; r < 4; r++) m[r] = fmaxf(m[r], __shfl_xor(m[r], off));
        }
        mx4[rt] = m;
    }
    #pragma unroll
    for (int rt = 0; rt < 4; rt++) {
        v4f dsum = {};
        #pragma unroll
        for (int ct = 0; ct < 4; ct++) {
            #pragma unroll
            for (int r = 0; r < 4; r++) {
                float e = __expf(S[rt][ct][r] - mx4[rt][r]);
                dsum[r] += e;
                Pl[(rt * 16 + q * 4 + r) * 72 + ct * 16 + c] = (__bf16)e;
            }
        }
        #pragma unroll
        for (int off = 1; off < 16; off <<= 1) {
            #pragma unroll
            for (int r = 0; r < 4; r++) dsum[r] += __shfl_xor(dsum[r], off);
        }
        #pragma unroll
        for (int r = 0; r < 4; r++) inv4[rt][r] = 1.f / dsum[r];
    }
    __syncthreads();
    v4f O[4][2] = {};
    #pragma unroll
    for (int k2 = 0; k2 < 2; k2++) {
        v8bf pa[4], pb[2];
        #pragma unroll
        for (int rt = 0; rt < 4; rt++)
            pa[rt] = *(const v8bf*)(Pl + (rt * 16 + c) * 72 + k2 * 32 + q * 8);
        #pragma unroll
        for (int ct = 0; ct < 2; ct++)
            pb[ct] = *(const v8bf*)(VTl + (ct * 16 + c) * 72 + k2 * 32 + q * 8);
        #pragma unroll
        for (int rt = 0; rt < 4; rt++)
        #pragma unroll
        for (int ct = 0; ct < 2; ct++)
            O[rt][ct] = __builtin_amdgcn_mfma_f32_16x16x32_bf16(pa[rt], pb[ct], O[rt][ct], 0, 0, 0);
    }
    __bf16* aop = ao + (size_t)(w * NTOK) * DIM + h * 32;
    #pragma unroll
    for (int rt = 0; rt < 4; rt++)
    #pragma unroll
    for (int r = 0; r < 4; r++) {
        int row = rt * 16 + q * 4 + r;
        if (row < NTOK) {
            #pragma unroll
            for (int ct = 0; ct < 2; ct++)
                aop[(size_t)row * DIM + ct * 16 + c] = (__bf16)(O[rt][ct][r] * inv4[rt][r]);
        }
    }
}

// ---------------------------------------------------------------------------
// Fallback fused MLP (used only if ws_size is too small for the hidden buf).
// ---------------------------------------------------------------------------
__global__ __launch_bounds__(256) void k_mlp(const float* __restrict__ x1,
                                             const float* __restrict__ n2g,
                                             const float* __restrict__ n2b,
                                             const __bf16* __restrict__ fc1T,
                                             const float* __restrict__ fc1b,
                                             const __bf16* __restrict__ fc2T,
                                             const float* __restrict__ fc2b,
                                             float* __restrict__ out) {
    __shared__ __align__(16) char sm[75776];
    __bf16* aT  = (__bf16*)sm;
    float*  lnf = (float*)(sm + 25600);
    __bf16* lB  = (__bf16*)(sm + 25600);
    __bf16* lH  = (__bf16*)(sm + 40960);
    int tid = threadIdx.x;
    int m0 = blockIdx.x * 64;
    int wv = tid >> 6, lane = tid & 63;
    int lrow = lane & 15, lq = lane >> 4;
    int wm = (wv >> 1) * 32, wnb = wv & 1;
    #pragma unroll
    for (int c = 0; c < 12; c++) {
        int idx = tid + c * 256;
        int row = idx / 48, c4 = (idx - row * 48) * 4;
        *(float4*)(lnf + row * 196 + c4) = *(const float4*)(x1 + (size_t)(m0 + row) * DIM + c4);
    }
    __syncthreads();
    {
        int row = tid >> 2, part = tid & 3;
        const float* rp = lnf + row * 196;
        float s = 0.f, s2 = 0.f;
        for (int i = part * 48; i < part * 48 + 48; i++) { float vv = rp[i]; s += vv; s2 += vv * vv; }
        s += __shfl_xor(s, 1); s2 += __shfl_xor(s2, 1);
        s += __shfl_xor(s, 2); s2 += __shfl_xor(s2, 2);
        float mu = s * (1.f / 192.f);
        float rstd = rsqrtf(s2 * (1.f / 192.f) - mu * mu + 1e-5f);
        __bf16* ap = aT + row * 200;
        for (int i = part * 48; i < part * 48 + 48; i++)
            ap[i] = (__bf16)((rp[i] - mu) * rstd * n2g[i] + n2b[i]);
    }
    __syncthreads();
    v4f yacc[2][6] = {};
    for (int hc = 0; hc < 6; hc++) {
        v4f hacc[2][4] = {};
        for (int ks = 0; ks < 6; ks++) {
            #pragma unroll
            for (int c = 0; c < 2; c++) {
                int nrow = (tid >> 2) + c * 64;
                int kc = (tid & 3) * 8;
                *(v8bf*)(lB + nrow * 40 + kc) =
                    *(const v8bf*)(fc1T + (size_t)(hc * 128 + nrow) * DIM + ks * 32 + kc);
            }
            __syncthreads();
            #pragma unroll
            for (int a = 0; a < 2; a++) {
                v8bf af = *(const v8bf*)(aT + (wm + a * 16 + lrow) * 200 + ks * 32 + lq * 8);
                #pragma unroll
                for (int b = 0; b < 4; b++) {
                    v8bf bf = *(const v8bf*)(lB + (wnb * 64 + b * 16 + lrow) * 40 + lq * 8);
                    hacc[a][b] = __builtin_amdgcn_mfma_f32_16x16x32_bf16(af, bf, hacc[a][b], 0, 0, 0);
                }
            }
            __syncthreads();
        }
        #pragma unroll
        for (int a = 0; a < 2; a++)
        #pragma unroll
        for (int b = 0; b < 4; b++)
        #pragma unroll
        for (int r = 0; r < 4; r++) {
            int row = wm + a * 16 + lq * 4 + r;
            int col = wnb * 64 + b * 16 + lrow;
            float hv = hacc[a][b][r] + fc1b[hc * 128 + col];
            float ge = 0.5f * hv * (1.f + erff(hv * 0.70710678118654752f));
            lH[row * 136 + col] = (__bf16)ge;
        }
        __syncthreads();
        for (int k2 = 0; k2 < 4; k2++) {
            #pragma unroll
            for (int c = 0; c < 3; c++) {
                int nrow = (tid >> 2) + c * 64;
                int kc = (tid & 3) * 8;
                *(v8bf*)(lB + nrow * 40 + kc) =
                    *(const v8bf*)(fc2T + (size_t)nrow * HID + hc * 128 + k2 * 32 + kc);
            }
            __syncthreads();
            #pragma unroll
            for (int a = 0; a < 2; a++) {
                v8bf af = *(const v8bf*)(lH + (wm + a * 16 + lrow) * 136 + k2 * 32 + lq * 8);
                #pragma unroll
                for (int b = 0; b < 6; b++) {
                    v8bf bf = *(const v8bf*)(lB + (wnb * 96 + b * 16 + lrow) * 40 + lq * 8);
                    yacc[a][b] = __builtin_amdgcn_mfma_f32_16x16x32_bf16(af, bf, yacc[a][b], 0, 0, 0);
                }
            }
            __syncthreads();
        }
    }
    #pragma unroll
    for (int a = 0; a < 2; a++)
    #pragma unroll
    for (int b = 0; b < 6; b++)
    #pragma unroll
    for (int r = 0; r < 4; r++) {
        int grow = m0 + wm + a * 16 + lq * 4 + r;
        int col = wnb * 96 + b * 16 + lrow;
        float vv = yacc[a][b][r] + fc2b[col] + x1[(size_t)grow * DIM + col];
        out[(size_t)grow * DIM + col] = vv;
    }
}

// ---------------------------------------------------------------------------
extern "C" void kernel_launch(void* const* d_in, const int* in_sizes, int n_in,
                              void* d_out, int out_size, void* d_ws, size_t ws_size,
                              hipStream_t stream) {
    const float* x      = (const float*)d_in[0];
    const float* n1g    = (const float*)d_in[1];
    const float* n1b    = (const float*)d_in[2];
    const float* qkv_w  = (const float*)d_in[3];
    const float* qkv_b  = (const float*)d_in[4];
    const float* rpb    = (const float*)d_in[5];
    const float* proj_w = (const float*)d_in[6];
    const float* proj_b = (const float*)d_in[7];
    const float* n2g    = (const float*)d_in[8];
    const float* n2b    = (const float*)d_in[9];
    const float* fc1_w  = (const float*)d_in[10];
    const float* fc1_b  = (const float*)d_in[11];
    const float* fc2_w  = (const float*)d_in[12];
    const float* fc2_b  = (const float*)d_in[13];
    float* outp = (float*)d_out;

    char* ws = (char*)d_ws;
    const size_t SZA = (size_t)MTOT * DIM * 2;      //  38,535,168
    const size_t WSZ = 884736;                      // transposed weights
    const size_t BSZ = 4 * HEADS * 64 * 64 * 4;     // bias tables 393,216

    const size_t need_big = 7 * SZA + WSZ + BSZ;    // ~271 MB (same as round 4)
    bool big = (ws_size >= need_big);

    // big-path coloring (units of SZA):
    //   x1: 0..2 (f32)   xw: 2..3   q/k/v: 3..6   a2: 6..7   hid: 2..6 (after
    //   xw & qkv die)    weights/bias-tables: 7..
    float*  x1; __bf16* xw; __bf16* qb; __bf16* a2; __bf16* hid; char* wbase;
    if (big) {
        x1    = (float*)(ws);
        xw    = (__bf16*)(ws + 2 * SZA);
        qb    = (__bf16*)(ws + 3 * SZA);
        a2    = (__bf16*)(ws + 6 * SZA);
        hid   = (__bf16*)(ws + 2 * SZA);
        wbase = ws + 7 * SZA;
    } else {
        xw    = (__bf16*)(ws);
        qb    = (__bf16*)(ws + SZA);
        x1    = (float*)(ws + SZA);                 // overlays q+k after attn
        a2    = nullptr; hid = nullptr;
        wbase = ws + 4 * SZA;
    }
    __bf16* qkvT  = (__bf16*)wbase;
    __bf16* projT = qkvT + 576 * 192;
    __bf16* fc1T  = projT + 192 * 192;
    __bf16* fc2T  = fc1T + 768 * 192;
    float*  btab  = (float*)(fc2T + 768 * 192);

    k_transpose<<<(192 * 576 + 255) / 256, 256, 0, stream>>>(qkv_w, qkvT, 192, 576);
    k_transpose<<<(192 * 192 + 255) / 256, 256, 0, stream>>>(proj_w, projT, 192, 192);
    k_transpose<<<(192 * 768 + 255) / 256, 256, 0, stream>>>(fc1_w, fc1T, 192, 768);
    k_transpose<<<(768 * 192 + 255) / 256, 256, 0, stream>>>(fc2_w, fc2T, 768, 192);
    k_bias<<<dim3(4, HEADS), 256, 0, stream>>>(rpb, btab);

    k_ln1win<<<MTOT / 4, 256, 0, stream>>>(x, n1g, n1b, xw);

    // qkv: [M x 192] x [576 x 192]^T -> scatter q/k/v [w,h,t,32]
    k_gemm128<192, 576, 0><<<dim3(MTOT / 128, 5), 256, 0, stream>>>(
        xw, qkvT, qkv_b, qb, nullptr, nullptr, nullptr);

    k_attn_mfma<<<NWIN * HEADS, 64, 0, stream>>>(qb, btab, xw);

    if (big) {
        // proj + residual + LN2 fused: writes x1 f32 and a2 bf16 (image order)
        k_projln<<<MTOT / 128, 256, 0, stream>>>(
            xw, projT, proj_b, x, n2g, n2b, x1, a2);
        // fc1: [M x 192] x [768 x 192]^T -> hid bf16 (GELU)
        k_gemm128<192, 768, 2><<<dim3(MTOT / 128, 6), 256, 0, stream>>>(
            a2, fc1T, fc1_b, hid, nullptr, nullptr, nullptr);
        // fc2: [M x 768] x [192 x 768]^T -> out f32 (+bias +x1), hid read once
        k_fc2<<<MTOT / 128, 256, 0, stream>>>(hid, fc2T, fc2_b, x1, outp);
    } else {
        k_gemm128<192, 192, 1><<<dim3(MTOT / 128, 2), 256, 0, stream>>>(
            xw, projT, proj_b, nullptr, nullptr, x1, x);
        k_mlp<<<MTOT / 64, 256, 0, stream>>>(x1, n2g, n2b, fc1T, fc1_b, fc2T, fc2_b, outp);
    }
}